// Round 1
// baseline (291.493 us; speedup 1.0000x reference)
//
#include <hip/hip_runtime.h>
#include <hip/hip_bf16.h>
#include <stdint.h>

// SimpleAttention: B=4, S=2048, D_IN=D_OUT=1024, fp32 in/out, bf16 MFMA compute.
// out = softmax((x@Wq+bq)(x@Wk+bk)^T / 32) @ (x@Wv+bv)
//
// R11: k_qkv and k_scores moved to a 256x256xBK64 8-wave "8-phase" core
// (T2 XOR-swizzle + T3/T4 counted-vmcnt phases + T5 setprio), breaking the
// 128^2/one-barrier-per-K-step ~900 TF structure ceiling. QKV is one plain
// GEMM M=8192 x N=3072 (Wt contiguous [3072][1024]), epilogue per z.
// Schedule: per K-tile 4 phases x 16 MFMA; reads of a buffer finish by end
// of phase 2, so tile t+2 pair0 issues at phase 3; one vmcnt(2) per tile
// (vmcnt(0) only at the tail), raw s_barriers so no compiler drain.
// k_pv stays on the verified gemm128 path this round.

#define Bsz 4
#define Ssz 2048
#define Dsz 1024

typedef __attribute__((ext_vector_type(8))) short short8;
typedef __attribute__((ext_vector_type(4))) float floatx4;
typedef const __attribute__((address_space(1))) void* gptr_t;
typedef __attribute__((address_space(3))) void* lptr_t;

__device__ __forceinline__ ushort f32_to_bf16(float f) {
    union { float f; uint32_t u; } c; c.f = f;
    uint32_t u = c.u;
    u += 0x7fffu + ((u >> 16) & 1u);
    return (ushort)(u >> 16);
}

__device__ __forceinline__ void glds16(const ushort* g, ushort* l) {
    __builtin_amdgcn_global_load_lds((gptr_t)g, (lptr_t)l, 16, 0, 0);
}

__device__ __forceinline__ void barrier_raw() {
    asm volatile("" ::: "memory");
    __builtin_amdgcn_s_barrier();
    asm volatile("" ::: "memory");
}

// ---------------------------------------------------------------------------
// 256x256x(NT*64) 8-phase GEMM core. 512 threads = 8 waves (2M x 4N).
// Wave owns 128x64 of C: acc[mi 0..7][ni 0..3], 16x16 frags.
// LDS: A,B each [2 dbuf][256 rows][64 cols] bf16 = 128 KB total.
// Row chunking: 8 chunks of 8 bf16 (16 B); physical chunk = logical ^ (row&7)
// -> conflict-free ds_read_b128 (each 8-lane group covers all 32 banks).
// global_load_lds writes linearly; source column is inverse-swizzled.
// ---------------------------------------------------------------------------
#define MFMA_QUAD(MB, NB)                                                              \
    _Pragma("unroll")                                                                  \
    for (int m_ = 0; m_ < 4; m_++) {                                                   \
        _Pragma("unroll")                                                              \
        for (int n_ = 0; n_ < 2; n_++) {                                               \
            acc[(MB) * 4 + m_][(NB) * 2 + n_] = __builtin_amdgcn_mfma_f32_16x16x32_bf16( \
                af[m_][0], bf[(NB) * 2 + n_][0], acc[(MB) * 4 + m_][(NB) * 2 + n_], 0, 0, 0); \
            acc[(MB) * 4 + m_][(NB) * 2 + n_] = __builtin_amdgcn_mfma_f32_16x16x32_bf16( \
                af[m_][1], bf[(NB) * 2 + n_][1], acc[(MB) * 4 + m_][(NB) * 2 + n_], 0, 0, 0); \
        }                                                                              \
    }

#define LOAD_A(half)                                                                   \
    _Pragma("unroll")                                                                  \
    for (int m_ = 0; m_ < 4; m_++) {                                                   \
        af[m_][0] = *(const short8*)(lA + aBase + ((half) * 4 + m_) * 1024 + c0);      \
        af[m_][1] = *(const short8*)(lA + aBase + ((half) * 4 + m_) * 1024 + c1);      \
    }

#define LOAD_B(pn)                                                                     \
    _Pragma("unroll")                                                                  \
    for (int n_ = 0; n_ < 2; n_++) {                                                   \
        bf[(pn) * 2 + n_][0] = *(const short8*)(lB + bBase + ((pn) * 2 + n_) * 1024 + c0); \
        bf[(pn) * 2 + n_][1] = *(const short8*)(lB + bBase + ((pn) * 2 + n_) * 1024 + c1); \
    }

template <int NT>
__device__ __forceinline__ void gemm256_core(
    const ushort* __restrict__ A, int lda,
    const ushort* __restrict__ Bt, int ldb,
    int row0, int col0, floatx4 (&acc)[8][4])
{
    __shared__ __align__(16) ushort lsA[2][256 * 64];   // 64 KB
    __shared__ __align__(16) ushort lsB[2][256 * 64];   // 64 KB

    const int tid  = threadIdx.x;
    const int lane = tid & 63;
    const int wave = tid >> 6;
    const int wr   = (wave >> 2) * 128;
    const int wc   = (wave & 3) * 64;
    const int m16  = lane & 15;
    const int quad = lane >> 4;

#pragma unroll
    for (int i = 0; i < 8; i++)
#pragma unroll
        for (int j = 0; j < 4; j++) acc[i][j] = (floatx4){0.f, 0.f, 0.f, 0.f};

    // staging: 512 thr x 16 B = 64 rows/op; 8 ops/tile (A:4, B:4) in 4 pairs
    const int sRow = tid >> 3;
    const int sC   = ((tid & 7) ^ (sRow & 7)) * 8;      // inverse swizzle on source
    const ushort* aSrc = A  + (size_t)(row0 + sRow) * lda + sC;
    const ushort* bSrc = Bt + (size_t)(col0 + sRow) * ldb + sC;
    ushort* dA = &lsA[0][0] + tid * 8;
    ushort* dB = &lsB[0][0] + tid * 8;

    // frag read offsets (swizzle on read)
    const int aBase = (wr + m16) * 64;
    const int bBase = (wc + m16) * 64;
    const int c0 = (quad ^ (m16 & 7)) * 8;
    const int c1 = c0 ^ 32;

    auto stage = [&](int kt, int buf, int pair) {
        const size_t ko = (size_t)kt * 64;
        const int bo = buf * 16384;
        if (pair == 0) {
            glds16(aSrc + ko,                      dA + bo);
            glds16(aSrc + ko + (size_t)64 * lda,   dA + bo + 4096);
        } else if (pair == 1) {
            glds16(aSrc + ko + (size_t)128 * lda,  dA + bo + 8192);
            glds16(aSrc + ko + (size_t)192 * lda,  dA + bo + 12288);
        } else if (pair == 2) {
            glds16(bSrc + ko,                      dB + bo);
            glds16(bSrc + ko + (size_t)64 * ldb,   dB + bo + 4096);
        } else {
            glds16(bSrc + ko + (size_t)128 * ldb,  dB + bo + 8192);
            glds16(bSrc + ko + (size_t)192 * ldb,  dB + bo + 12288);
        }
    };

    // prologue: tile0 fully + tile1 pair0; wait tile0 (2 newer in flight ok)
    stage(0, 0, 0); stage(0, 0, 1); stage(0, 0, 2); stage(0, 0, 3);
    stage(1, 1, 0);
    asm volatile("s_waitcnt vmcnt(2)" ::: "memory");
    barrier_raw();

    short8 af[4][2], bf[4][2];

    for (int kt = 0; kt < NT; ++kt) {
        const int buf = kt & 1;
        const ushort* lA = &lsA[buf][0];
        const ushort* lB = &lsB[buf][0];
        const bool pf1 = (kt + 1 < NT);

        // ---- phase 0: A half0 (8 rd) + B pair0 (4 rd); stage next pair1
        LOAD_A(0);
        LOAD_B(0);
        if (pf1) stage(kt + 1, buf ^ 1, 1);
        barrier_raw();
        __builtin_amdgcn_s_setprio(1);
        MFMA_QUAD(0, 0);
        __builtin_amdgcn_s_setprio(0);
        barrier_raw();

        // ---- phase 1: B pair1 (4 rd); stage next pair2
        LOAD_B(1);
        if (pf1) stage(kt + 1, buf ^ 1, 2);
        barrier_raw();
        __builtin_amdgcn_s_setprio(1);
        MFMA_QUAD(0, 1);
        __builtin_amdgcn_s_setprio(0);
        barrier_raw();

        // ---- phase 2: A half1 (8 rd, overwrites af); stage next pair3
        LOAD_A(1);
        if (pf1) stage(kt + 1, buf ^ 1, 3);
        barrier_raw();
        __builtin_amdgcn_s_setprio(1);
        MFMA_QUAD(1, 0);
        __builtin_amdgcn_s_setprio(0);
        barrier_raw();

        // ---- phase 3: no reads; stage tile kt+2 pair0 into freed buf regions
        if (kt + 2 < NT) stage(kt + 2, buf, 0);
        __builtin_amdgcn_s_setprio(1);
        MFMA_QUAD(1, 1);
        __builtin_amdgcn_s_setprio(0);
        // tile-boundary wait: kt+1's 8 ops done; 2 newer (kt+2 pair0) in flight
        if (kt + 2 < NT)      { asm volatile("s_waitcnt vmcnt(2)" ::: "memory"); }
        else if (kt + 1 < NT) { asm volatile("s_waitcnt vmcnt(0)" ::: "memory"); }
        barrier_raw();
    }
}

// ---------------------------------------------------------------------------
// Fused QKV as one GEMM: [8192 x 1024] x [3072 x 1024]^T. Grid 384 (32M x 12N),
// XCD-chunked swizzle (384 % 8 == 0). Epilogue per z = bn>>2.
// ---------------------------------------------------------------------------
__global__ __launch_bounds__(512, 2) void k_qkv256(
    const ushort* __restrict__ xb, const ushort* __restrict__ Wt,
    const float* __restrict__ bq, const float* __restrict__ bk,
    const float* __restrict__ bv, ushort* __restrict__ QKV,
    ushort* __restrict__ Vt)
{
    const int bid = blockIdx.x;                 // 0..383
    const int wg  = (bid & 7) * 48 + (bid >> 3);
    const int bm  = wg & 31;                    // M tile 0..31
    const int bn  = wg >> 5;                    // N tile 0..11
    const int row0  = bm * 256;
    const int col0n = bn * 256;                 // 0..3071 across QKV

    floatx4 acc[8][4];
    gemm256_core<16>(xb, Dsz, Wt, Dsz, row0, col0n, acc);

    const int tid  = threadIdx.x;
    const int lane = tid & 63;
    const int wave = tid >> 6;
    const int wr   = (wave >> 2) * 128;
    const int wc   = (wave & 3) * 64;
    const int m16  = lane & 15;
    const int quad = lane >> 4;

    const int z     = bn >> 2;
    const int colz0 = col0n & 1023;

    if (z == 0) {
#pragma unroll
        for (int ni = 0; ni < 4; ni++) {
            const int colz = colz0 + wc + ni * 16 + m16;
            const float bqv = bq[colz];
#pragma unroll
            for (int mi = 0; mi < 8; mi++) {
                const int grow0 = row0 + wr + mi * 16 + quad * 4;
#pragma unroll
                for (int j = 0; j < 4; j++)
                    QKV[(size_t)(grow0 + j) * Dsz + colz] =
                        f32_to_bf16((acc[mi][ni][j] + bqv) * 0.03125f);
            }
        }
    } else if (z == 1) {
        ushort* Kout = QKV + (size_t)(Bsz * Ssz) * Dsz;
#pragma unroll
        for (int ni = 0; ni < 4; ni++) {
            const int colz = colz0 + wc + ni * 16 + m16;
            const float bkv = bk[colz];
#pragma unroll
            for (int mi = 0; mi < 8; mi++) {
                const int grow0 = row0 + wr + mi * 16 + quad * 4;
#pragma unroll
                for (int j = 0; j < 4; j++)
                    Kout[(size_t)(grow0 + j) * Dsz + colz] =
                        f32_to_bf16(acc[mi][ni][j] + bkv);
            }
        }
    } else {
        // V transposed -> Vt[b][e][s], ushort4 stores along s
#pragma unroll
        for (int ni = 0; ni < 4; ni++) {
            const int colz = colz0 + wc + ni * 16 + m16;
            const float bvv = bv[colz];
#pragma unroll
            for (int mi = 0; mi < 8; mi++) {
                const int grow0 = row0 + wr + mi * 16 + quad * 4;
                ushort4 vpack;
                vpack.x = f32_to_bf16(acc[mi][ni][0] + bvv);
                vpack.y = f32_to_bf16(acc[mi][ni][1] + bvv);
                vpack.z = f32_to_bf16(acc[mi][ni][2] + bvv);
                vpack.w = f32_to_bf16(acc[mi][ni][3] + bvv);
                const int batch = grow0 >> 11;
                const int s0 = grow0 & (Ssz - 1);
                *(ushort4*)&Vt[(size_t)batch * Dsz * Ssz + (size_t)colz * Ssz + s0] = vpack;
            }
        }
    }
}

// ---------------------------------------------------------------------------
// scores[b] = Q[b] @ K[b]^T (Q pre-scaled by 1/32). Grid 256 (8M x 8N x 4b).
// ---------------------------------------------------------------------------
__global__ __launch_bounds__(512, 2) void k_scores256(
    const ushort* __restrict__ QKV, float* __restrict__ scores)
{
    const int bid = blockIdx.x;                 // 0..255
    const int wg  = (bid & 7) * 32 + (bid >> 3);
    const int b   = wg >> 6;
    const int bm  = (wg >> 3) & 7;
    const int bn  = wg & 7;
    const int row0 = bm * 256;
    const int col0 = bn * 256;

    const ushort* Q  = QKV + (size_t)b * Ssz * Dsz;
    const ushort* Kb = QKV + (size_t)(Bsz + b) * Ssz * Dsz;

    floatx4 acc[8][4];
    gemm256_core<16>(Q, Dsz, Kb, Dsz, row0, col0, acc);

    const int tid  = threadIdx.x;
    const int lane = tid & 63;
    const int wave = tid >> 6;
    const int wr   = (wave >> 2) * 128;
    const int wc   = (wave & 3) * 64;
    const int m16  = lane & 15;
    const int quad = lane >> 4;

    float* out = scores + (size_t)b * Ssz * Ssz;
#pragma unroll
    for (int ni = 0; ni < 4; ni++) {
        const int gcol = col0 + wc + ni * 16 + m16;
#pragma unroll
        for (int mi = 0; mi < 8; mi++) {
            const int grow0 = row0 + wr + mi * 16 + quad * 4;
#pragma unroll
            for (int j = 0; j < 4; j++)
                out[(size_t)(grow0 + j) * Ssz + gcol] = acc[mi][ni][j];
        }
    }
}

// ---------------------------------------------------------------------------
// Generic 128x128 GEMM (R7): C = A(MxK) * Bt(NxK)^T, bf16 in, fp32/bf16 out.
// (kept for k_pv this round)
// ---------------------------------------------------------------------------
template <bool OUT_BF16>
__device__ __forceinline__ void gemm128(
    int bx, int by,
    const ushort* __restrict__ A, int lda,
    const ushort* __restrict__ Bt, int ldb,
    int K,
    void* __restrict__ Cout, int ldc,
    const float* __restrict__ bias, float alpha)
{
    __shared__ ushort lsA[2][128 * 32];
    __shared__ ushort lsB[2][128 * 32];

    const int tid  = threadIdx.x;
    const int row0 = by * 128;
    const int col0 = bx * 128;

    const int lane = tid & 63;
    const int wave = tid >> 6;
    const int wr   = (wave >> 1) * 64;
    const int wc   = (wave & 1) * 64;
    const int m16  = lane & 15;
    const int quad = lane >> 4;

    floatx4 acc[4][4];
#pragma unroll
    for (int i = 0; i < 4; i++)
#pragma unroll
        for (int j = 0; j < 4; j++) acc[i][j] = (floatx4){0.f, 0.f, 0.f, 0.f};

    const int srow = tid >> 2;
    const int skc  = (tid & 3) ^ ((srow >> 1) & 3);
    const ushort* ga = A  + (size_t)(row0 + srow) * lda + skc * 8;
    const ushort* gb = Bt + (size_t)(col0 + srow) * ldb + skc * 8;
    const int aoff = (quad ^ ((m16 >> 1) & 3)) * 8;

    __builtin_amdgcn_global_load_lds((gptr_t)(ga),                     (lptr_t)(lsA[0] + tid * 8),        16, 0, 0);
    __builtin_amdgcn_global_load_lds((gptr_t)(ga + (size_t)64 * lda), (lptr_t)(lsA[0] + 2048 + tid * 8), 16, 0, 0);
    __builtin_amdgcn_global_load_lds((gptr_t)(gb),                     (lptr_t)(lsB[0] + tid * 8),        16, 0, 0);
    __builtin_amdgcn_global_load_lds((gptr_t)(gb + (size_t)64 * ldb), (lptr_t)(lsB[0] + 2048 + tid * 8), 16, 0, 0);

    for (int k0 = 0; k0 < K; k0 += 32) {
        const int cur = (k0 >> 5) & 1;
        __syncthreads();
        if (k0 + 32 < K) {
            const int nxt = cur ^ 1;
            const int kn = k0 + 32;
            __builtin_amdgcn_global_load_lds((gptr_t)(ga + kn),                     (lptr_t)(lsA[nxt] + tid * 8),        16, 0, 0);
            __builtin_amdgcn_global_load_lds((gptr_t)(ga + kn + (size_t)64 * lda), (lptr_t)(lsA[nxt] + 2048 + tid * 8), 16, 0, 0);
            __builtin_amdgcn_global_load_lds((gptr_t)(gb + kn),                     (lptr_t)(lsB[nxt] + tid * 8),        16, 0, 0);
            __builtin_amdgcn_global_load_lds((gptr_t)(gb + kn + (size_t)64 * ldb), (lptr_t)(lsB[nxt] + 2048 + tid * 8), 16, 0, 0);
        }

        short8 af[4], bfr[4];
#pragma unroll
        for (int mi = 0; mi < 4; mi++)
            af[mi] = *(const short8*)&lsA[cur][(wr + mi * 16 + m16) * 32 + aoff];
#pragma unroll
        for (int ni = 0; ni < 4; ni++)
            bfr[ni] = *(const short8*)&lsB[cur][(wc + ni * 16 + m16) * 32 + aoff];
#pragma unroll
        for (int mi = 0; mi < 4; mi++)
#pragma unroll
            for (int ni = 0; ni < 4; ni++)
                acc[mi][ni] = __builtin_amdgcn_mfma_f32_16x16x32_bf16(af[mi], bfr[ni], acc[mi][ni], 0, 0, 0);
    }

#pragma unroll
    for (int ni = 0; ni < 4; ni++) {
        const int gcol = col0 + wc + ni * 16 + m16;
        const float bv = bias ? bias[gcol] : 0.0f;
#pragma unroll
        for (int mi = 0; mi < 4; mi++) {
            const int grow0 = row0 + wr + mi * 16 + quad * 4;
#pragma unroll
            for (int j = 0; j < 4; j++) {
                float v = (acc[mi][ni][j] + bv) * alpha;
                if (OUT_BF16)
                    ((ushort*)Cout)[(size_t)(grow0 + j) * ldc + gcol] = f32_to_bf16(v);
                else
                    ((float*)Cout)[(size_t)(grow0 + j) * ldc + gcol] = v;
            }
        }
    }
}

// ---------------------------------------------------------------------------
// prep: x fp32 -> bf16
__global__ __launch_bounds__(256) void k_cvt_x(const float* __restrict__ x, ushort* __restrict__ xb) {
    int i = (blockIdx.x * 256 + threadIdx.x) * 4;
    float4 v = *(const float4*)(x + i);
    ushort4 o;
    o.x = f32_to_bf16(v.x); o.y = f32_to_bf16(v.y);
    o.z = f32_to_bf16(v.z); o.w = f32_to_bf16(v.w);
    *(ushort4*)(xb + i) = o;
}

// prep: W [K][N] fp32 -> Wt [N][K] bf16, for each of Wq/Wk/Wv (z)
__global__ __launch_bounds__(256) void k_wt(const float* __restrict__ Wq, const float* __restrict__ Wk,
                                            const float* __restrict__ Wv, ushort* __restrict__ Wt) {
    __shared__ float tile[32][33];
    const int z = blockIdx.z;
    const float* W = (z == 0) ? Wq : ((z == 1) ? Wk : Wv);
    ushort* out = Wt + (size_t)z * Dsz * Dsz;
    const int kb = blockIdx.y * 32, nb = blockIdx.x * 32;
    const int tx = threadIdx.x, ty = threadIdx.y;   // 32x8
#pragma unroll
    for (int j = 0; j < 32; j += 8)
        tile[ty + j][tx] = W[(size_t)(kb + ty + j) * Dsz + nb + tx];
    __syncthreads();
#pragma unroll
    for (int j = 0; j < 32; j += 8)
        out[(size_t)(nb + ty + j) * Dsz + kb + tx] = f32_to_bf16(tile[tx][ty + j]);
}

// row softmax, fp32 row -> bf16 P written in place over the row's first half
__global__ __launch_bounds__(256) void k_softmax(float* __restrict__ scores) {
    const size_t row = blockIdx.x;
    float* rp = scores + row * Ssz;
    const int tid = threadIdx.x;
    float4 v0 = ((const float4*)rp)[tid];
    float4 v1 = ((const float4*)rp)[tid + 256];
    float m = fmaxf(fmaxf(fmaxf(v0.x, v0.y), fmaxf(v0.z, v0.w)),
                    fmaxf(fmaxf(v1.x, v1.y), fmaxf(v1.z, v1.w)));
#pragma unroll
    for (int o = 32; o > 0; o >>= 1) m = fmaxf(m, __shfl_down(m, o, 64));
    __shared__ float redm[4];
    if ((tid & 63) == 0) redm[tid >> 6] = m;
    __syncthreads();
    const float rm = fmaxf(fmaxf(redm[0], redm[1]), fmaxf(redm[2], redm[3]));
    v0.x = __expf(v0.x - rm); v0.y = __expf(v0.y - rm);
    v0.z = __expf(v0.z - rm); v0.w = __expf(v0.w - rm);
    v1.x = __expf(v1.x - rm); v1.y = __expf(v1.y - rm);
    v1.z = __expf(v1.z - rm); v1.w = __expf(v1.w - rm);
    float s = v0.x + v0.y + v0.z + v0.w + v1.x + v1.y + v1.z + v1.w;
#pragma unroll
    for (int o = 32; o > 0; o >>= 1) s += __shfl_down(s, o, 64);
    __shared__ float reds[4];
    if ((tid & 63) == 0) reds[tid >> 6] = s;
    __syncthreads();
    const float inv = 1.0f / (reds[0] + reds[1] + reds[2] + reds[3]);
    ushort4 o0, o1;
    o0.x = f32_to_bf16(v0.x * inv); o0.y = f32_to_bf16(v0.y * inv);
    o0.z = f32_to_bf16(v0.z * inv); o0.w = f32_to_bf16(v0.w * inv);
    o1.x = f32_to_bf16(v1.x * inv); o1.y = f32_to_bf16(v1.y * inv);
    o1.z = f32_to_bf16(v1.z * inv); o1.w = f32_to_bf16(v1.w * inv);
    ((ushort4*)rp)[tid] = o0;
    ((ushort4*)rp)[tid + 256] = o1;
}

// out[b] = P[b] @ V[b]. Grid (8,16,4), R7 XCD swizzle. Bt = Vt row-major [d][s].
__global__ __launch_bounds__(256) void k_pv(const float* __restrict__ scores, const ushort* __restrict__ Vt,
                                            float* __restrict__ out) {
    const int b = blockIdx.z;
    const int lin = blockIdx.y * 8 + blockIdx.x;
    const int c = lin & 7, m = lin >> 3;
    const int by = 2 * c + (m & 1);
    const int bx = m >> 1;
    const ushort* P = (const ushort*)(scores + (size_t)b * Ssz * Ssz);
    const ushort* Bt = Vt + (size_t)b * Dsz * Ssz;
    gemm128<false>(bx, by, P, 2 * Ssz, Bt, Ssz, Ssz, out + (size_t)b * Ssz * Dsz, Dsz, nullptr, 1.0f);
}

// ---------------------------------------------------------------------------
extern "C" void kernel_launch(void* const* d_in, const int* in_sizes, int n_in,
                              void* d_out, int out_size, void* d_ws, size_t ws_size,
                              hipStream_t stream) {
    const float* x  = (const float*)d_in[0];
    const float* Wq = (const float*)d_in[1];
    const float* bq = (const float*)d_in[2];
    const float* Wk = (const float*)d_in[3];
    const float* bk = (const float*)d_in[4];
    const float* Wv = (const float*)d_in[5];
    const float* bv = (const float*)d_in[6];
    float* out = (float*)d_out;

    // workspace layout (bytes)
    char* ws = (char*)d_ws;
    ushort* xb     = (ushort*)(ws);                                   // 16,777,216
    ushort* Wt     = (ushort*)(ws + 16777216);                        //  6,291,456
    ushort* QKV    = (ushort*)(ws + 23068672);                        // 50,331,648 (V region unused)
    ushort* Vt     = (ushort*)(ws + 73400320);                        // 16,777,216
    float*  scores = (float*) (ws + 90177536);                        // 67,108,864 -> 157,286,400 total

    k_cvt_x<<<dim3(Bsz * Ssz * Dsz / (256 * 4)), dim3(256), 0, stream>>>(x, xb);
    k_wt<<<dim3(32, 32, 3), dim3(32, 8), 0, stream>>>(Wq, Wk, Wv, Wt);
    k_qkv256<<<dim3(384), dim3(512), 0, stream>>>(xb, Wt, bq, bk, bv, QKV, Vt);
    k_scores256<<<dim3(256), dim3(512), 0, stream>>>(QKV, scores);
    k_softmax<<<dim3(Bsz * Ssz), dim3(256), 0, stream>>>(scores);
    k_pv<<<dim3(Dsz / 128, Ssz / 128, Bsz), dim3(256), 0, stream>>>(scores, Vt, out);
}